// Round 11
// baseline (643.941 us; speedup 1.0000x reference)
//
#include <hip/hip_runtime.h>
#include <hip/hip_fp16.h>
#include <stdint.h>

#define T_REL 3
#define F_IN  128
#define F_HID 128
#define F_OUT 64

#define BSHIFT 7                 // 128 dst nodes per bucket
#define BRANGE (1 << BSHIFT)
#define BCAP   3072              // mean 2048, sigma ~45 -> 22 sigma headroom
#define KB_MAX 1024
#define CHUNK_E 4096             // edges per bin block
#define NB_MAX 512
#define PADCAP 520               // per-bucket slack: 128 nodes * 4 + align

#define FP8_SCALE     16.0f     // fold x16 into table, /16 into di
#define FP8_INV_SCALE (1.0f / 16.0f)

typedef _Float16 f16x8 __attribute__((ext_vector_type(8)));
typedef float    f32x4v __attribute__((ext_vector_type(4)));
typedef int      i4v   __attribute__((ext_vector_type(4)));
typedef float    f4v   __attribute__((ext_vector_type(4)));
typedef float    f2v   __attribute__((ext_vector_type(2)));

// ===========================================================================
// Pass 1: bin edges by dst bucket.  bHist/lStart stored TRANSPOSED
// ([t][bucket][binblock]).  colSum atomics removed — bucket_scan derives
// bucket totals from bHist rows instead.
// ===========================================================================
__global__ __launch_bounds__(256) void bin_dense_kernel(
    int* __restrict__ bHist, int* __restrict__ lStart,
    uint32_t* __restrict__ binned, const int* __restrict__ edges,
    int E, int KB, int NB)
{
    int t = blockIdx.y, blk = blockIdx.x, tid = threadIdx.x;
    int e0 = blk * CHUNK_E;
    int cnt = min(CHUNK_E, E - e0);

    __shared__ int hist[KB_MAX];
    __shared__ int cursor[KB_MAX];
    __shared__ int sh[256];
    __shared__ uint32_t obuf[CHUNK_E];

    for (int b = tid; b < KB_MAX; b += 256) hist[b] = 0;
    __syncthreads();

    const int* srcA = edges + (size_t)(t * 2) * E;
    const int* dstA = edges + (size_t)(t * 2 + 1) * E;

    uint32_t pk[16]; int bk[16];
#pragma unroll
    for (int r = 0; r < 16; ++r) {
        int i = r * 256 + tid;
        if (i < cnt) {
            int s = srcA[e0 + i], d = dstA[e0 + i];
            bk[r] = d >> BSHIFT;
            pk[r] = ((uint32_t)(d & (BRANGE - 1)) << 17) | (uint32_t)s;
            atomicAdd(&hist[bk[r]], 1);
        } else bk[r] = -1;
    }
    __syncthreads();

    int b4 = tid * 4;
    int v0 = hist[b4], v1 = hist[b4 + 1], v2 = hist[b4 + 2], v3 = hist[b4 + 3];
    sh[tid] = v0 + v1 + v2 + v3;
    __syncthreads();
    for (int off = 1; off < 256; off <<= 1) {
        int x = (tid >= off) ? sh[tid - off] : 0;
        __syncthreads(); sh[tid] += x; __syncthreads();
    }
    int texcl = tid ? sh[tid - 1] : 0;
    cursor[b4] = texcl;
    cursor[b4 + 1] = texcl + v0;
    cursor[b4 + 2] = texcl + v0 + v1;
    cursor[b4 + 3] = texcl + v0 + v1 + v2;
    __syncthreads();

    // transposed layout: [t][b][blk]
    int* bh = bHist + (size_t)t * KB * NB;
    int* ls = lStart + (size_t)t * KB * NB;
    for (int b = tid; b < KB; b += 256) {
        bh[(size_t)b * NB + blk] = hist[b];
        ls[(size_t)b * NB + blk] = cursor[b];
    }
    __syncthreads();

#pragma unroll
    for (int r = 0; r < 16; ++r) {
        if (bk[r] >= 0) {
            int pos = atomicAdd(&cursor[bk[r]], 1);
            obuf[pos] = pk[r];
        }
    }
    __syncthreads();

    for (int i = tid; i < cnt; i += 256)
        binned[(size_t)t * E + e0 + i] = obuf[i];
}

// ===========================================================================
// Pass 2: per-bucket totals (row-sum of transposed bHist) -> padded
// capacity scan -> bucketStart.  Replaces the colSum memset+atomics.
// ===========================================================================
__global__ __launch_bounds__(1024) void bucket_scan_kernel(
    const int* __restrict__ bHist, int* __restrict__ bucketStart,
    int KB, int NB)
{
    int t = blockIdx.x, tid = threadIdx.x;
    __shared__ int sh[1024];
    int v = 0;
    if (tid < KB) {
        const int* bh = bHist + ((size_t)t * KB + tid) * NB;
        int s = 0;
        for (int r = 0; r < NB; ++r) s += bh[r];
        v = ((s + 3) & ~3) + PADCAP;
    }
    sh[tid] = v;
    __syncthreads();
    for (int off = 1; off < 1024; off <<= 1) {
        int x = (tid >= off) ? sh[tid - off] : 0;
        __syncthreads(); sh[tid] += x; __syncthreads();
    }
    if (tid < KB) bucketStart[t * (KB + 1) + tid] = sh[tid] - v;
}

__global__ __launch_bounds__(256) void bucket_gather_sort_kernel(
    const int* __restrict__ bHist, const int* __restrict__ lStart,
    const int* __restrict__ bucketStart, const uint32_t* __restrict__ binned,
    int* __restrict__ srcs, int* __restrict__ rp, int* __restrict__ rpe,
    float* __restrict__ dinv, int KB, int NB, int N, int E, int EP)
{
    int t = blockIdx.y, b = blockIdx.x, tid = threadIdx.x;
    int base = b << BSHIFT;
    int bstart = bucketStart[t * (KB + 1) + b];

    __shared__ uint32_t eL[BCAP];
    __shared__ int bc[NB_MAX], bo[NB_MAX];
    __shared__ int sh[256];
    __shared__ int hist[BRANGE], excl[BRANGE], cur[BRANGE];

    // transposed layout: coalesced row read
    const int* bh = bHist + ((size_t)t * KB + b) * NB;
    const int* ls = lStart + ((size_t)t * KB + b) * NB;

    for (int r = tid; r < NB_MAX; r += 256) bc[r] = 0;
    if (tid < BRANGE) hist[tid] = 0;
    __syncthreads();
    for (int r = tid; r < NB; r += 256) bc[r] = bh[r];
    __syncthreads();

    int i2 = tid * 2;
    int u0 = bc[i2], u1 = bc[i2 + 1];
    sh[tid] = u0 + u1;
    __syncthreads();
    for (int off = 1; off < 256; off <<= 1) {
        int x = (tid >= off) ? sh[tid - off] : 0;
        __syncthreads(); sh[tid] += x; __syncthreads();
    }
    int te = tid ? sh[tid - 1] : 0;
    bo[i2] = te; bo[i2 + 1] = te + u0;
    __syncthreads();
    int cnt = sh[255]; if (cnt > BCAP) cnt = BCAP;

    for (int r = tid; r < NB; r += 256) {
        int c = bc[r];
        if (!c) continue;
        int off = bo[r];
        const uint32_t* sp = binned + (size_t)t * E + (size_t)r * CHUNK_E + ls[r];
        for (int i = 0; i < c; ++i) {
            int p = off + i;
            if (p < BCAP) {
                uint32_t v = sp[i];
                eL[p] = v;
                atomicAdd(&hist[v >> 17], 1);
            }
        }
    }
    __syncthreads();

    // scan PADDED per-node sizes: pad = (deg + 1(self) + 3) & ~3
    if (tid < BRANGE) excl[tid] = (hist[tid] + 4) & ~3;
    __syncthreads();
    for (int off = 1; off < BRANGE; off <<= 1) {
        int x = (tid < BRANGE && tid >= off) ? excl[tid - off] : 0;
        __syncthreads();
        if (tid < BRANGE) excl[tid] += x;
        __syncthreads();
    }
    if (tid < BRANGE) {
        int deg = hist[tid];
        int p = (deg + 4) & ~3;
        int e_ = excl[tid] - p;          // exclusive prefix of padded sizes
        cur[tid] = e_;
        int g = base + tid;
        if (g < N) {
            rp [(size_t)t * N + g] = bstart + e_;
            rpe[(size_t)t * N + g] = bstart + e_ + p;
            dinv[(size_t)t * N + g] = rsqrtf(1.0f + (float)deg);
            int* seg = srcs + (size_t)t * EP + bstart + e_;
            seg[deg] = g;                                 // self-loop edge
            for (int k = deg + 1; k < p; ++k) seg[k] = N; // sentinel -> zero row
        }
    }
    __syncthreads();

    int* so = srcs + (size_t)t * EP + bstart;
    for (int i = tid; i < cnt; i += 256) {
        uint32_t v = eL[i];
        int slot = atomicAdd(&cur[v >> 17], 1);
        so[slot] = (int)(v & 0x1FFFF);
    }
}

// ===========================================================================
// MFMA fp16 GEMM, layer 1 -> FP8 E4M3 table, relation loop fused.  (R10)
// ===========================================================================
__global__ __launch_bounds__(256) void mfma_gemm_fp8_kernel(
    const float* __restrict__ X, const float* __restrict__ W,
    uint8_t* __restrict__ H8, const float* __restrict__ dinv, int N)
{
    constexpr int BM = 64, BN = 128, K = 128;
    constexpr int XST = K + 8;
    constexpr int WST = K + 8;

    __shared__ _Float16 Xs[BM * XST];
    __shared__ _Float16 Ws[BN * WST];

    int tid = threadIdx.x;
    int row0 = blockIdx.x * BM;

#pragma unroll
    for (int u = 0; u < (BM * K / 4) / 256; ++u) {
        int i = u * 256 + tid;
        int r = i >> 5, c4 = i & 31;
        int gr = row0 + r;
        float4 v = make_float4(0.f, 0.f, 0.f, 0.f);
        if (gr < N) v = reinterpret_cast<const float4*>(X)[(size_t)gr * (K / 4) + c4];
        _Float16* xp = &Xs[r * XST + c4 * 4];
        xp[0] = (_Float16)v.x; xp[1] = (_Float16)v.y;
        xp[2] = (_Float16)v.z; xp[3] = (_Float16)v.w;
    }
    __syncthreads();

    int wv = tid >> 6, lane = tid & 63, quad = lane >> 4, lr = lane & 15;
    int rw = wv * 16;

    f16x8 a[4];
#pragma unroll
    for (int kk = 0; kk < 4; ++kk)
        a[kk] = *reinterpret_cast<const f16x8*>(&Xs[(rw + lr) * XST + quad * 8 + kk * 32]);

    for (int t = 0; t < T_REL; ++t) {
        const float* Wt = W + (size_t)t * K * BN;
        for (int idx = tid; idx < K * BN; idx += 256) {
            int k = idx >> 7, n = idx & (BN - 1);
            Ws[n * WST + k] = (_Float16)Wt[idx];
        }
        __syncthreads();

        const float* dvt = dinv + (size_t)t * N;
        uint8_t*     Ht  = H8 + (size_t)t * (N + 1) * BN;
        float ds[4];
#pragma unroll
        for (int reg = 0; reg < 4; ++reg) {
            int gr = row0 + rw + quad * 4 + reg;
            ds[reg] = (gr < N) ? dvt[gr] * FP8_SCALE : 0.f;  // row N -> 0
        }

#pragma unroll
        for (int ct = 0; ct < BN / 16; ++ct) {
            f32x4v acc = {0.f, 0.f, 0.f, 0.f};
#pragma unroll
            for (int kk = 0; kk < 4; ++kk) {
                f16x8 bf = *reinterpret_cast<const f16x8*>(&Ws[(ct * 16 + lr) * WST + quad * 8 + kk * 32]);
                acc = __builtin_amdgcn_mfma_f32_16x16x32_f16(a[kk], bf, acc, 0, 0, 0);
            }
#pragma unroll
            for (int reg = 0; reg < 4; ++reg) {
                int gr = row0 + rw + quad * 4 + reg;
                if (gr <= N) {
                    float v = acc[reg] * ds[reg];
                    int pk = __builtin_amdgcn_cvt_pk_fp8_f32(v, v, 0, false);
                    Ht[(size_t)gr * BN + ct * 16 + lr] = (uint8_t)(pk & 0xff);
                }
            }
        }
        __syncthreads();      // Ws reuse next t
    }
}

// ===========================================================================
// MFMA fp16 GEMM, layer 2, relation loop fused.  (R10)
// ===========================================================================
__global__ __launch_bounds__(256) void mfma_gemm_h16_kernel(
    const __half* __restrict__ X, const float* __restrict__ W,
    __half* __restrict__ H, const float* __restrict__ dinv, int N)
{
    constexpr int BM = 64, BN = 64, K = 128;
    constexpr int XST = K + 8;
    constexpr int WST = K + 8;

    __shared__ _Float16 Xs[BM * XST];
    __shared__ _Float16 Ws[BN * WST];

    int tid = threadIdx.x;
    int row0 = blockIdx.x * BM;

#pragma unroll
    for (int u = 0; u < 4; ++u) {               // 64*128 halves / (256*8)
        int idx = u * 256 + tid;
        int r = idx >> 4, c8 = idx & 15;
        int gr = row0 + r;
        int4 v = make_int4(0, 0, 0, 0);
        if (gr < N)
            v = *reinterpret_cast<const int4*>(X + (size_t)gr * K + c8 * 8);
        *reinterpret_cast<int4*>(&Xs[r * XST + c8 * 8]) = v;
    }
    __syncthreads();

    int wv = tid >> 6, lane = tid & 63, quad = lane >> 4, lr = lane & 15;
    int rw = wv * 16;

    f16x8 a[4];
#pragma unroll
    for (int kk = 0; kk < 4; ++kk)
        a[kk] = *reinterpret_cast<const f16x8*>(&Xs[(rw + lr) * XST + quad * 8 + kk * 32]);

    for (int t = 0; t < T_REL; ++t) {
        const float* Wt = W + (size_t)t * K * BN;
        for (int idx = tid; idx < K * BN; idx += 256) {
            int k = idx >> 6, n = idx & (BN - 1);
            Ws[n * WST + k] = (_Float16)Wt[idx];
        }
        __syncthreads();

        const float* dvt = dinv + (size_t)t * N;
        __half*      Ht  = H + (size_t)t * (N + 1) * BN;
        float ds[4];
#pragma unroll
        for (int reg = 0; reg < 4; ++reg) {
            int gr = row0 + rw + quad * 4 + reg;
            ds[reg] = (gr < N) ? dvt[gr] : 0.f;
        }

#pragma unroll
        for (int ct = 0; ct < BN / 16; ++ct) {
            f32x4v acc = {0.f, 0.f, 0.f, 0.f};
#pragma unroll
            for (int kk = 0; kk < 4; ++kk) {
                f16x8 bf = *reinterpret_cast<const f16x8*>(&Ws[(ct * 16 + lr) * WST + quad * 8 + kk * 32]);
                acc = __builtin_amdgcn_mfma_f32_16x16x32_f16(a[kk], bf, acc, 0, 0, 0);
            }
#pragma unroll
            for (int reg = 0; reg < 4; ++reg) {
                int gr = row0 + rw + quad * 4 + reg;
                if (gr <= N) Ht[(size_t)gr * BN + ct * 16 + lr] = (__half)(acc[reg] * ds[reg]);
            }
        }
        __syncthreads();
    }
}

// ===========================================================================
// Layer-1 gather (pull, fp8 table): verbatim R9/R10.
// ===========================================================================
__global__ __launch_bounds__(256) void gather_l1_kernel(
    __half* __restrict__ h16, const uint8_t* __restrict__ H8,
    const float* __restrict__ dinv, const int* __restrict__ rp,
    const int* __restrict__ rpe, const int* __restrict__ srcs,
    const float* __restrict__ bias, int N, int EP)
{
    constexpr int F = 128;

    int wave = threadIdx.x >> 6;
    int lane = threadIdx.x & 63;
    int sub  = lane >> 3;                  // 0..7 node slot
    int lcol = lane & 7;                   // 8 lanes per row
    int i = (blockIdx.x * 4 + wave) * 8 + sub;
    if (i >= N) return;
    uint32_t c = (uint32_t)lcol * 16;      // fp8-index within row

    float r[16];
#pragma unroll
    for (int k = 0; k < 16; ++k) r[k] = 0.f;

    for (int t = 0; t < T_REL; ++t) {
        const uint8_t* Ht = H8 + (size_t)t * (N + 1) * F;
        const int*     st = srcs + (size_t)t * EP;
        float di = dinv[(size_t)t * N + i] * FP8_INV_SCALE;

        float s[16];
#pragma unroll
        for (int k = 0; k < 16; ++k) s[k] = 0.f;

        auto rowld = [&](int sidx) -> uint4 {
            return *reinterpret_cast<const uint4*>(Ht + ((uint32_t)sidx * (uint32_t)F + c));
        };
        auto acc16 = [&](uint4 q) {
            f2v a;
            a = __builtin_amdgcn_cvt_pk_f32_fp8(q.x, false); s[0] += a.x;  s[1] += a.y;
            a = __builtin_amdgcn_cvt_pk_f32_fp8(q.x, true);  s[2] += a.x;  s[3] += a.y;
            a = __builtin_amdgcn_cvt_pk_f32_fp8(q.y, false); s[4] += a.x;  s[5] += a.y;
            a = __builtin_amdgcn_cvt_pk_f32_fp8(q.y, true);  s[6] += a.x;  s[7] += a.y;
            a = __builtin_amdgcn_cvt_pk_f32_fp8(q.z, false); s[8] += a.x;  s[9] += a.y;
            a = __builtin_amdgcn_cvt_pk_f32_fp8(q.z, true);  s[10] += a.x; s[11] += a.y;
            a = __builtin_amdgcn_cvt_pk_f32_fp8(q.w, false); s[12] += a.x; s[13] += a.y;
            a = __builtin_amdgcn_cvt_pk_f32_fp8(q.w, true);  s[14] += a.x; s[15] += a.y;
        };

        int j   = rp [(size_t)t * N + i];
        int end = rpe[(size_t)t * N + i];

        for (; j + 8 <= end; j += 8) {
            i4v pa = __builtin_nontemporal_load(reinterpret_cast<const i4v*>(st + j));
            i4v pb = __builtin_nontemporal_load(reinterpret_cast<const i4v*>(st + j + 4));
            uint4 q0 = rowld(pa[0]), q1 = rowld(pa[1]), q2 = rowld(pa[2]), q3 = rowld(pa[3]);
            uint4 q4 = rowld(pb[0]), q5 = rowld(pb[1]), q6 = rowld(pb[2]), q7 = rowld(pb[3]);
            acc16(q0); acc16(q1); acc16(q2); acc16(q3);
            acc16(q4); acc16(q5); acc16(q6); acc16(q7);
        }
        if (j < end) {                      // exactly one aligned 4-group
            i4v pa = __builtin_nontemporal_load(reinterpret_cast<const i4v*>(st + j));
            uint4 q0 = rowld(pa[0]), q1 = rowld(pa[1]), q2 = rowld(pa[2]), q3 = rowld(pa[3]);
            acc16(q0); acc16(q1); acc16(q2); acc16(q3);
        }

        const float4 b0 = *reinterpret_cast<const float4*>(bias + (size_t)t * F + c);
        const float4 b1 = *reinterpret_cast<const float4*>(bias + (size_t)t * F + c + 4);
        const float4 b2 = *reinterpret_cast<const float4*>(bias + (size_t)t * F + c + 8);
        const float4 b3 = *reinterpret_cast<const float4*>(bias + (size_t)t * F + c + 12);
        r[0]  += s[0]  * di + b0.x; r[1]  += s[1]  * di + b0.y;
        r[2]  += s[2]  * di + b0.z; r[3]  += s[3]  * di + b0.w;
        r[4]  += s[4]  * di + b1.x; r[5]  += s[5]  * di + b1.y;
        r[6]  += s[6]  * di + b1.z; r[7]  += s[7]  * di + b1.w;
        r[8]  += s[8]  * di + b2.x; r[9]  += s[9]  * di + b2.y;
        r[10] += s[10] * di + b2.z; r[11] += s[11] * di + b2.w;
        r[12] += s[12] * di + b3.x; r[13] += s[13] * di + b3.y;
        r[14] += s[14] * di + b3.z; r[15] += s[15] * di + b3.w;
    }

    constexpr float inv3 = 1.0f / 3.0f;
    __half2 h[8];
#pragma unroll
    for (int k = 0; k < 8; ++k)
        h[k] = __floats2half2_rn(fmaxf(r[2 * k] * inv3, 0.f),
                                 fmaxf(r[2 * k + 1] * inv3, 0.f));
    i4v o0, o1;
    o0[0] = *reinterpret_cast<int*>(&h[0]);
    o0[1] = *reinterpret_cast<int*>(&h[1]);
    o0[2] = *reinterpret_cast<int*>(&h[2]);
    o0[3] = *reinterpret_cast<int*>(&h[3]);
    o1[0] = *reinterpret_cast<int*>(&h[4]);
    o1[1] = *reinterpret_cast<int*>(&h[5]);
    o1[2] = *reinterpret_cast<int*>(&h[6]);
    o1[3] = *reinterpret_cast<int*>(&h[7]);
    __half* op = h16 + (size_t)i * F + c;
    __builtin_nontemporal_store(o0, reinterpret_cast<i4v*>(op));
    __builtin_nontemporal_store(o1, reinterpret_cast<i4v*>(op + 8));
}

// ===========================================================================
// Layer-2 gather (pull, fp16 F=64 table): verbatim R9/R10.
// ===========================================================================
__global__ __launch_bounds__(256) void gather_l2_kernel(
    float* __restrict__ out, const __half* __restrict__ H,
    const float* __restrict__ dinv, const int* __restrict__ rp,
    const int* __restrict__ rpe, const int* __restrict__ srcs,
    const float* __restrict__ bias, int N, int EP)
{
    constexpr int F = 64, LPR = 8;

    int wave = threadIdx.x >> 6;
    int lane = threadIdx.x & 63;
    int sub  = lane >> 3;
    int lcol = lane & (LPR - 1);
    int i = (blockIdx.x * 4 + wave) * 8 + sub;
    if (i >= N) return;
    uint32_t c = (uint32_t)lcol * 8;         // half-index within row

    float r0 = 0.f, r1 = 0.f, r2 = 0.f, r3 = 0.f,
          r4 = 0.f, r5 = 0.f, r6 = 0.f, r7 = 0.f;

    for (int t = 0; t < T_REL; ++t) {
        const __half* Ht = H + (size_t)t * (N + 1) * F;
        const int*    st = srcs + (size_t)t * EP;
        float di = dinv[(size_t)t * N + i];

        float s0 = 0.f, s1 = 0.f, s2 = 0.f, s3 = 0.f,
              s4 = 0.f, s5 = 0.f, s6 = 0.f, s7 = 0.f;

        auto rowld = [&](int s) -> float4 {
            return *reinterpret_cast<const float4*>(Ht + ((uint32_t)s * (uint32_t)F + c));
        };
        auto acc8 = [&](float4 q) {
            const __half2* hp = reinterpret_cast<const __half2*>(&q);
            float2 f0 = __half22float2(hp[0]);
            float2 f1 = __half22float2(hp[1]);
            float2 f2 = __half22float2(hp[2]);
            float2 f3 = __half22float2(hp[3]);
            s0 += f0.x; s1 += f0.y; s2 += f1.x; s3 += f1.y;
            s4 += f2.x; s5 += f2.y; s6 += f3.x; s7 += f3.y;
        };

        int j   = rp [(size_t)t * N + i];
        int end = rpe[(size_t)t * N + i];

        for (; j + 8 <= end; j += 8) {
            i4v pa = __builtin_nontemporal_load(reinterpret_cast<const i4v*>(st + j));
            i4v pb = __builtin_nontemporal_load(reinterpret_cast<const i4v*>(st + j + 4));
            float4 q0 = rowld(pa[0]), q1 = rowld(pa[1]), q2 = rowld(pa[2]), q3 = rowld(pa[3]);
            float4 q4 = rowld(pb[0]), q5 = rowld(pb[1]), q6 = rowld(pb[2]), q7 = rowld(pb[3]);
            acc8(q0); acc8(q1); acc8(q2); acc8(q3);
            acc8(q4); acc8(q5); acc8(q6); acc8(q7);
        }
        if (j < end) {
            i4v pa = __builtin_nontemporal_load(reinterpret_cast<const i4v*>(st + j));
            float4 q0 = rowld(pa[0]), q1 = rowld(pa[1]), q2 = rowld(pa[2]), q3 = rowld(pa[3]);
            acc8(q0); acc8(q1); acc8(q2); acc8(q3);
        }

        const float4 b0 = *reinterpret_cast<const float4*>(bias + (size_t)t * F + c);
        const float4 b1 = *reinterpret_cast<const float4*>(bias + (size_t)t * F + c + 4);
        r0 += s0 * di + b0.x; r1 += s1 * di + b0.y;
        r2 += s2 * di + b0.z; r3 += s3 * di + b0.w;
        r4 += s4 * di + b1.x; r5 += s5 * di + b1.y;
        r6 += s6 * di + b1.z; r7 += s7 * di + b1.w;
    }

    constexpr float inv3 = 1.0f / 3.0f;
    f4v o0 = {r0 * inv3, r1 * inv3, r2 * inv3, r3 * inv3};
    f4v o1 = {r4 * inv3, r5 * inv3, r6 * inv3, r7 * inv3};
    float* op = out + (size_t)i * F + c;
    __builtin_nontemporal_store(o0, reinterpret_cast<f4v*>(op));
    __builtin_nontemporal_store(o1, reinterpret_cast<f4v*>(op + 4));
}

// ===========================================================================
extern "C" void kernel_launch(void* const* d_in, const int* in_sizes, int n_in,
                              void* d_out, int out_size, void* d_ws, size_t ws_size,
                              hipStream_t stream) {
    const float* x     = (const float*)d_in[0];
    const int*   edges = (const int*)  d_in[1];
    const float* W1    = (const float*)d_in[2];
    const float* b1    = (const float*)d_in[3];
    const float* W2    = (const float*)d_in[4];
    const float* b2    = (const float*)d_in[5];
    float* out = (float*)d_out;

    const int N  = in_sizes[0] / F_IN;
    const int E  = in_sizes[1] / (T_REL * 2);
    const int KB = (N + BRANGE - 1) >> BSHIFT;       // 782 buckets/relation
    const int NB = (E + CHUNK_E - 1) / CHUNK_E;      // 391 bin blocks/relation
    const int EP = E + (PADCAP + 4) * KB + 256;      // padded edges/relation

    auto align256 = [](size_t x_) { return (x_ + 255) & ~(size_t)255; };
    char* p = (char*)d_ws;
    float*   dinv   = (float*)p;   p += align256((size_t)T_REL * N * 4);
    int*     rp     = (int*)p;     p += align256((size_t)T_REL * N * 4);
    int*     rpe    = (int*)p;     p += align256((size_t)T_REL * N * 4);
    int*     bstart = (int*)p;     p += align256((size_t)T_REL * (KB + 1) * 4);
    int*     srcs   = (int*)p;     p += align256((size_t)T_REL * EP * 4);
    uint8_t* H8     = (uint8_t*)p; p += align256((size_t)T_REL * (N + 1) * F_HID);
    __half*  H2     = (__half*)p;  p += align256((size_t)T_REL * (N + 1) * F_OUT * 2);
    // Shared scratch region: h16 (25.6 MB, written by gather_l1) overlays the
    // CSR-build scratch (binned 19.2 + bHist/lStart 7.3 = 26.5 MB), which is
    // fully consumed by bucket_gather_sort before gather_l1 runs.
    char* share = p;
    __half*   h16    = (__half*)share;
    uint32_t* binned = (uint32_t*)share;
    char* q = share + align256((size_t)T_REL * E * 4);
    int*      bHist  = (int*)q;      q += align256((size_t)T_REL * NB * KB * 4);
    int*      lStart = (int*)q;      q += align256((size_t)T_REL * NB * KB * 4);
    size_t shareSz = (size_t)(q - share);
    size_t h16Sz   = (size_t)N * F_HID * 2;
    p = share + align256(shareSz > h16Sz ? shareSz : h16Sz);

    // ---- CSR build (no memset, no colSum atomics) ----
    {
        dim3 g(NB, T_REL);
        bin_dense_kernel<<<g, 256, 0, stream>>>(bHist, lStart, binned,
                                                edges, E, KB, NB);
    }
    bucket_scan_kernel<<<T_REL, 1024, 0, stream>>>(bHist, bstart, KB, NB);
    {
        dim3 g(KB, T_REL);
        bucket_gather_sort_kernel<<<g, 256, 0, stream>>>(
            bHist, lStart, bstart, binned, srcs, rp, rpe, dinv, KB, NB, N, E, EP);
    }

    // ---- layer 1: H8 = fp8((x@W1[t])*dinv*16), h16 = relu(mean+bias) ----
    mfma_gemm_fp8_kernel<<<N / 64 + 1, 256, 0, stream>>>(x, W1, H8, dinv, N);
    gather_l1_kernel<<<(N + 31) / 32, 256, 0, stream>>>(
        h16, H8, dinv, rp, rpe, srcs, b1, N, EP);

    // ---- layer 2: H2 = (h16@W2[t])*dinv fp16, out = mean+bias fp32 ----
    mfma_gemm_h16_kernel<<<N / 64 + 1, 256, 0, stream>>>(h16, W2, H2, dinv, N);
    gather_l2_kernel<<<(N + 31) / 32, 256, 0, stream>>>(
        out, H2, dinv, rp, rpe, srcs, b2, N, EP);
}

// Round 12
// 489.376 us; speedup vs baseline: 1.3158x; 1.3158x over previous
//
#include <hip/hip_runtime.h>
#include <hip/hip_fp16.h>
#include <stdint.h>

#define T_REL 3
#define F_IN  128
#define F_HID 128
#define F_OUT 64

#define BSHIFT 7                 // 128 dst nodes per bucket
#define BRANGE (1 << BSHIFT)
#define BCAP   3072              // mean 2048, sigma ~45 -> 22 sigma headroom
#define KB_MAX 1024
#define CHUNK_E 4096             // edges per bin block
#define NB_MAX 512
#define PADCAP 520               // per-bucket slack: 128 nodes * 4 + align

#define FP8_SCALE     16.0f     // fold x16 into table, /16 into di
#define FP8_INV_SCALE (1.0f / 16.0f)

typedef _Float16 f16x8 __attribute__((ext_vector_type(8)));
typedef float    f32x4v __attribute__((ext_vector_type(4)));
typedef int      i4v   __attribute__((ext_vector_type(4)));
typedef float    f4v   __attribute__((ext_vector_type(4)));
typedef float    f2v   __attribute__((ext_vector_type(2)));

// ===========================================================================
// Pass 1: bin edges by dst bucket.  bHist/lStart stored TRANSPOSED
// ([t][bucket][binblock]).  No colSum atomics (colsum_kernel derives totals).
// ===========================================================================
__global__ __launch_bounds__(256) void bin_dense_kernel(
    int* __restrict__ bHist, int* __restrict__ lStart,
    uint32_t* __restrict__ binned, const int* __restrict__ edges,
    int E, int KB, int NB)
{
    int t = blockIdx.y, blk = blockIdx.x, tid = threadIdx.x;
    int e0 = blk * CHUNK_E;
    int cnt = min(CHUNK_E, E - e0);

    __shared__ int hist[KB_MAX];
    __shared__ int cursor[KB_MAX];
    __shared__ int sh[256];
    __shared__ uint32_t obuf[CHUNK_E];

    for (int b = tid; b < KB_MAX; b += 256) hist[b] = 0;
    __syncthreads();

    const int* srcA = edges + (size_t)(t * 2) * E;
    const int* dstA = edges + (size_t)(t * 2 + 1) * E;

    uint32_t pk[16]; int bk[16];
#pragma unroll
    for (int r = 0; r < 16; ++r) {
        int i = r * 256 + tid;
        if (i < cnt) {
            int s = srcA[e0 + i], d = dstA[e0 + i];
            bk[r] = d >> BSHIFT;
            pk[r] = ((uint32_t)(d & (BRANGE - 1)) << 17) | (uint32_t)s;
            atomicAdd(&hist[bk[r]], 1);
        } else bk[r] = -1;
    }
    __syncthreads();

    int b4 = tid * 4;
    int v0 = hist[b4], v1 = hist[b4 + 1], v2 = hist[b4 + 2], v3 = hist[b4 + 3];
    sh[tid] = v0 + v1 + v2 + v3;
    __syncthreads();
    for (int off = 1; off < 256; off <<= 1) {
        int x = (tid >= off) ? sh[tid - off] : 0;
        __syncthreads(); sh[tid] += x; __syncthreads();
    }
    int texcl = tid ? sh[tid - 1] : 0;
    cursor[b4] = texcl;
    cursor[b4 + 1] = texcl + v0;
    cursor[b4 + 2] = texcl + v0 + v1;
    cursor[b4 + 3] = texcl + v0 + v1 + v2;
    __syncthreads();

    // transposed layout: [t][b][blk]
    int* bh = bHist + (size_t)t * KB * NB;
    int* ls = lStart + (size_t)t * KB * NB;
    for (int b = tid; b < KB; b += 256) {
        bh[(size_t)b * NB + blk] = hist[b];
        ls[(size_t)b * NB + blk] = cursor[b];
    }
    __syncthreads();

#pragma unroll
    for (int r = 0; r < 16; ++r) {
        if (bk[r] >= 0) {
            int pos = atomicAdd(&cursor[bk[r]], 1);
            obuf[pos] = pk[r];
        }
    }
    __syncthreads();

    for (int i = tid; i < cnt; i += 256)
        binned[(size_t)t * E + e0 + i] = obuf[i];
}

// ===========================================================================
// Pass 2a: per-bucket totals — one WAVE per (t,bucket), coalesced row read
// of the transposed bHist + shuffle reduce.  2346 waves across the chip.
// ===========================================================================
__global__ __launch_bounds__(256) void colsum_kernel(
    const int* __restrict__ bHist, int* __restrict__ colSum, int KB, int NB)
{
    int w    = blockIdx.x * 4 + (threadIdx.x >> 6);   // global wave id = t*KB+b
    int lane = threadIdx.x & 63;
    if (w >= T_REL * KB) return;
    const int* bh = bHist + (size_t)w * NB;
    int s = 0;
    for (int r = lane; r < NB; r += 64) s += bh[r];
#pragma unroll
    for (int off = 32; off; off >>= 1) s += __shfl_down(s, off);
    if (lane == 0) colSum[w] = s;
}

// Pass 2b: exclusive scan of padded bucket capacities -> bucketStart.
__global__ __launch_bounds__(1024) void bucket_scan_kernel(
    const int* __restrict__ colSum, int* __restrict__ bucketStart, int KB)
{
    int t = blockIdx.x, tid = threadIdx.x;
    __shared__ int sh[1024];
    int v = 0;
    if (tid < KB) v = ((colSum[t * KB + tid] + 3) & ~3) + PADCAP;
    sh[tid] = v;
    __syncthreads();
    for (int off = 1; off < 1024; off <<= 1) {
        int x = (tid >= off) ? sh[tid - off] : 0;
        __syncthreads(); sh[tid] += x; __syncthreads();
    }
    if (tid < KB) bucketStart[t * (KB + 1) + tid] = sh[tid] - v;
}

__global__ __launch_bounds__(256) void bucket_gather_sort_kernel(
    const int* __restrict__ bHist, const int* __restrict__ lStart,
    const int* __restrict__ bucketStart, const uint32_t* __restrict__ binned,
    int* __restrict__ srcs, int* __restrict__ rp, int* __restrict__ rpe,
    float* __restrict__ dinv, int KB, int NB, int N, int E, int EP)
{
    int t = blockIdx.y, b = blockIdx.x, tid = threadIdx.x;
    int base = b << BSHIFT;
    int bstart = bucketStart[t * (KB + 1) + b];

    __shared__ uint32_t eL[BCAP];
    __shared__ int bc[NB_MAX], bo[NB_MAX];
    __shared__ int sh[256];
    __shared__ int hist[BRANGE], excl[BRANGE], cur[BRANGE];

    // transposed layout: coalesced row read
    const int* bh = bHist + ((size_t)t * KB + b) * NB;
    const int* ls = lStart + ((size_t)t * KB + b) * NB;

    for (int r = tid; r < NB_MAX; r += 256) bc[r] = 0;
    if (tid < BRANGE) hist[tid] = 0;
    __syncthreads();
    for (int r = tid; r < NB; r += 256) bc[r] = bh[r];
    __syncthreads();

    int i2 = tid * 2;
    int u0 = bc[i2], u1 = bc[i2 + 1];
    sh[tid] = u0 + u1;
    __syncthreads();
    for (int off = 1; off < 256; off <<= 1) {
        int x = (tid >= off) ? sh[tid - off] : 0;
        __syncthreads(); sh[tid] += x; __syncthreads();
    }
    int te = tid ? sh[tid - 1] : 0;
    bo[i2] = te; bo[i2 + 1] = te + u0;
    __syncthreads();
    int cnt = sh[255]; if (cnt > BCAP) cnt = BCAP;

    for (int r = tid; r < NB; r += 256) {
        int c = bc[r];
        if (!c) continue;
        int off = bo[r];
        const uint32_t* sp = binned + (size_t)t * E + (size_t)r * CHUNK_E + ls[r];
        for (int i = 0; i < c; ++i) {
            int p = off + i;
            if (p < BCAP) {
                uint32_t v = sp[i];
                eL[p] = v;
                atomicAdd(&hist[v >> 17], 1);
            }
        }
    }
    __syncthreads();

    // scan PADDED per-node sizes: pad = (deg + 1(self) + 3) & ~3
    if (tid < BRANGE) excl[tid] = (hist[tid] + 4) & ~3;
    __syncthreads();
    for (int off = 1; off < BRANGE; off <<= 1) {
        int x = (tid < BRANGE && tid >= off) ? excl[tid - off] : 0;
        __syncthreads();
        if (tid < BRANGE) excl[tid] += x;
        __syncthreads();
    }
    if (tid < BRANGE) {
        int deg = hist[tid];
        int p = (deg + 4) & ~3;
        int e_ = excl[tid] - p;          // exclusive prefix of padded sizes
        cur[tid] = e_;
        int g = base + tid;
        if (g < N) {
            rp [(size_t)t * N + g] = bstart + e_;
            rpe[(size_t)t * N + g] = bstart + e_ + p;
            dinv[(size_t)t * N + g] = rsqrtf(1.0f + (float)deg);
            int* seg = srcs + (size_t)t * EP + bstart + e_;
            seg[deg] = g;                                 // self-loop edge
            for (int k = deg + 1; k < p; ++k) seg[k] = N; // sentinel -> zero row
        }
    }
    __syncthreads();

    int* so = srcs + (size_t)t * EP + bstart;
    for (int i = tid; i < cnt; i += 256) {
        uint32_t v = eL[i];
        int slot = atomicAdd(&cur[v >> 17], 1);
        so[slot] = (int)(v & 0x1FFFF);
    }
}

// ===========================================================================
// MFMA fp16 GEMM, layer 1 -> FP8 E4M3 table, relation loop fused.
// ===========================================================================
__global__ __launch_bounds__(256) void mfma_gemm_fp8_kernel(
    const float* __restrict__ X, const float* __restrict__ W,
    uint8_t* __restrict__ H8, const float* __restrict__ dinv, int N)
{
    constexpr int BM = 64, BN = 128, K = 128;
    constexpr int XST = K + 8;
    constexpr int WST = K + 8;

    __shared__ _Float16 Xs[BM * XST];
    __shared__ _Float16 Ws[BN * WST];

    int tid = threadIdx.x;
    int row0 = blockIdx.x * BM;

#pragma unroll
    for (int u = 0; u < (BM * K / 4) / 256; ++u) {
        int i = u * 256 + tid;
        int r = i >> 5, c4 = i & 31;
        int gr = row0 + r;
        float4 v = make_float4(0.f, 0.f, 0.f, 0.f);
        if (gr < N) v = reinterpret_cast<const float4*>(X)[(size_t)gr * (K / 4) + c4];
        _Float16* xp = &Xs[r * XST + c4 * 4];
        xp[0] = (_Float16)v.x; xp[1] = (_Float16)v.y;
        xp[2] = (_Float16)v.z; xp[3] = (_Float16)v.w;
    }
    __syncthreads();

    int wv = tid >> 6, lane = tid & 63, quad = lane >> 4, lr = lane & 15;
    int rw = wv * 16;

    f16x8 a[4];
#pragma unroll
    for (int kk = 0; kk < 4; ++kk)
        a[kk] = *reinterpret_cast<const f16x8*>(&Xs[(rw + lr) * XST + quad * 8 + kk * 32]);

    for (int t = 0; t < T_REL; ++t) {
        const float* Wt = W + (size_t)t * K * BN;
        for (int idx = tid; idx < K * BN; idx += 256) {
            int k = idx >> 7, n = idx & (BN - 1);
            Ws[n * WST + k] = (_Float16)Wt[idx];
        }
        __syncthreads();

        const float* dvt = dinv + (size_t)t * N;
        uint8_t*     Ht  = H8 + (size_t)t * (N + 1) * BN;
        float ds[4];
#pragma unroll
        for (int reg = 0; reg < 4; ++reg) {
            int gr = row0 + rw + quad * 4 + reg;
            ds[reg] = (gr < N) ? dvt[gr] * FP8_SCALE : 0.f;  // row N -> 0
        }

#pragma unroll
        for (int ct = 0; ct < BN / 16; ++ct) {
            f32x4v acc = {0.f, 0.f, 0.f, 0.f};
#pragma unroll
            for (int kk = 0; kk < 4; ++kk) {
                f16x8 bf = *reinterpret_cast<const f16x8*>(&Ws[(ct * 16 + lr) * WST + quad * 8 + kk * 32]);
                acc = __builtin_amdgcn_mfma_f32_16x16x32_f16(a[kk], bf, acc, 0, 0, 0);
            }
#pragma unroll
            for (int reg = 0; reg < 4; ++reg) {
                int gr = row0 + rw + quad * 4 + reg;
                if (gr <= N) {
                    float v = acc[reg] * ds[reg];
                    int pk = __builtin_amdgcn_cvt_pk_fp8_f32(v, v, 0, false);
                    Ht[(size_t)gr * BN + ct * 16 + lr] = (uint8_t)(pk & 0xff);
                }
            }
        }
        __syncthreads();      // Ws reuse next t
    }
}

// ===========================================================================
// MFMA fp16 GEMM, layer 2, relation loop fused.
// ===========================================================================
__global__ __launch_bounds__(256) void mfma_gemm_h16_kernel(
    const __half* __restrict__ X, const float* __restrict__ W,
    __half* __restrict__ H, const float* __restrict__ dinv, int N)
{
    constexpr int BM = 64, BN = 64, K = 128;
    constexpr int XST = K + 8;
    constexpr int WST = K + 8;

    __shared__ _Float16 Xs[BM * XST];
    __shared__ _Float16 Ws[BN * WST];

    int tid = threadIdx.x;
    int row0 = blockIdx.x * BM;

#pragma unroll
    for (int u = 0; u < 4; ++u) {               // 64*128 halves / (256*8)
        int idx = u * 256 + tid;
        int r = idx >> 4, c8 = idx & 15;
        int gr = row0 + r;
        int4 v = make_int4(0, 0, 0, 0);
        if (gr < N)
            v = *reinterpret_cast<const int4*>(X + (size_t)gr * K + c8 * 8);
        *reinterpret_cast<int4*>(&Xs[r * XST + c8 * 8]) = v;
    }
    __syncthreads();

    int wv = tid >> 6, lane = tid & 63, quad = lane >> 4, lr = lane & 15;
    int rw = wv * 16;

    f16x8 a[4];
#pragma unroll
    for (int kk = 0; kk < 4; ++kk)
        a[kk] = *reinterpret_cast<const f16x8*>(&Xs[(rw + lr) * XST + quad * 8 + kk * 32]);

    for (int t = 0; t < T_REL; ++t) {
        const float* Wt = W + (size_t)t * K * BN;
        for (int idx = tid; idx < K * BN; idx += 256) {
            int k = idx >> 6, n = idx & (BN - 1);
            Ws[n * WST + k] = (_Float16)Wt[idx];
        }
        __syncthreads();

        const float* dvt = dinv + (size_t)t * N;
        __half*      Ht  = H + (size_t)t * (N + 1) * BN;
        float ds[4];
#pragma unroll
        for (int reg = 0; reg < 4; ++reg) {
            int gr = row0 + rw + quad * 4 + reg;
            ds[reg] = (gr < N) ? dvt[gr] : 0.f;
        }

#pragma unroll
        for (int ct = 0; ct < BN / 16; ++ct) {
            f32x4v acc = {0.f, 0.f, 0.f, 0.f};
#pragma unroll
            for (int kk = 0; kk < 4; ++kk) {
                f16x8 bf = *reinterpret_cast<const f16x8*>(&Ws[(ct * 16 + lr) * WST + quad * 8 + kk * 32]);
                acc = __builtin_amdgcn_mfma_f32_16x16x32_f16(a[kk], bf, acc, 0, 0, 0);
            }
#pragma unroll
            for (int reg = 0; reg < 4; ++reg) {
                int gr = row0 + rw + quad * 4 + reg;
                if (gr <= N) Ht[(size_t)gr * BN + ct * 16 + lr] = (__half)(acc[reg] * ds[reg]);
            }
        }
        __syncthreads();
    }
}

// ===========================================================================
// Layer-1 gather (pull, fp8 table): verbatim R9/R10.
// ===========================================================================
__global__ __launch_bounds__(256) void gather_l1_kernel(
    __half* __restrict__ h16, const uint8_t* __restrict__ H8,
    const float* __restrict__ dinv, const int* __restrict__ rp,
    const int* __restrict__ rpe, const int* __restrict__ srcs,
    const float* __restrict__ bias, int N, int EP)
{
    constexpr int F = 128;

    int wave = threadIdx.x >> 6;
    int lane = threadIdx.x & 63;
    int sub  = lane >> 3;                  // 0..7 node slot
    int lcol = lane & 7;                   // 8 lanes per row
    int i = (blockIdx.x * 4 + wave) * 8 + sub;
    if (i >= N) return;
    uint32_t c = (uint32_t)lcol * 16;      // fp8-index within row

    float r[16];
#pragma unroll
    for (int k = 0; k < 16; ++k) r[k] = 0.f;

    for (int t = 0; t < T_REL; ++t) {
        const uint8_t* Ht = H8 + (size_t)t * (N + 1) * F;
        const int*     st = srcs + (size_t)t * EP;
        float di = dinv[(size_t)t * N + i] * FP8_INV_SCALE;

        float s[16];
#pragma unroll
        for (int k = 0; k < 16; ++k) s[k] = 0.f;

        auto rowld = [&](int sidx) -> uint4 {
            return *reinterpret_cast<const uint4*>(Ht + ((uint32_t)sidx * (uint32_t)F + c));
        };
        auto acc16 = [&](uint4 q) {
            f2v a;
            a = __builtin_amdgcn_cvt_pk_f32_fp8(q.x, false); s[0] += a.x;  s[1] += a.y;
            a = __builtin_amdgcn_cvt_pk_f32_fp8(q.x, true);  s[2] += a.x;  s[3] += a.y;
            a = __builtin_amdgcn_cvt_pk_f32_fp8(q.y, false); s[4] += a.x;  s[5] += a.y;
            a = __builtin_amdgcn_cvt_pk_f32_fp8(q.y, true);  s[6] += a.x;  s[7] += a.y;
            a = __builtin_amdgcn_cvt_pk_f32_fp8(q.z, false); s[8] += a.x;  s[9] += a.y;
            a = __builtin_amdgcn_cvt_pk_f32_fp8(q.z, true);  s[10] += a.x; s[11] += a.y;
            a = __builtin_amdgcn_cvt_pk_f32_fp8(q.w, false); s[12] += a.x; s[13] += a.y;
            a = __builtin_amdgcn_cvt_pk_f32_fp8(q.w, true);  s[14] += a.x; s[15] += a.y;
        };

        int j   = rp [(size_t)t * N + i];
        int end = rpe[(size_t)t * N + i];

        for (; j + 8 <= end; j += 8) {
            i4v pa = __builtin_nontemporal_load(reinterpret_cast<const i4v*>(st + j));
            i4v pb = __builtin_nontemporal_load(reinterpret_cast<const i4v*>(st + j + 4));
            uint4 q0 = rowld(pa[0]), q1 = rowld(pa[1]), q2 = rowld(pa[2]), q3 = rowld(pa[3]);
            uint4 q4 = rowld(pb[0]), q5 = rowld(pb[1]), q6 = rowld(pb[2]), q7 = rowld(pb[3]);
            acc16(q0); acc16(q1); acc16(q2); acc16(q3);
            acc16(q4); acc16(q5); acc16(q6); acc16(q7);
        }
        if (j < end) {                      // exactly one aligned 4-group
            i4v pa = __builtin_nontemporal_load(reinterpret_cast<const i4v*>(st + j));
            uint4 q0 = rowld(pa[0]), q1 = rowld(pa[1]), q2 = rowld(pa[2]), q3 = rowld(pa[3]);
            acc16(q0); acc16(q1); acc16(q2); acc16(q3);
        }

        const float4 b0 = *reinterpret_cast<const float4*>(bias + (size_t)t * F + c);
        const float4 b1 = *reinterpret_cast<const float4*>(bias + (size_t)t * F + c + 4);
        const float4 b2 = *reinterpret_cast<const float4*>(bias + (size_t)t * F + c + 8);
        const float4 b3 = *reinterpret_cast<const float4*>(bias + (size_t)t * F + c + 12);
        r[0]  += s[0]  * di + b0.x; r[1]  += s[1]  * di + b0.y;
        r[2]  += s[2]  * di + b0.z; r[3]  += s[3]  * di + b0.w;
        r[4]  += s[4]  * di + b1.x; r[5]  += s[5]  * di + b1.y;
        r[6]  += s[6]  * di + b1.z; r[7]  += s[7]  * di + b1.w;
        r[8]  += s[8]  * di + b2.x; r[9]  += s[9]  * di + b2.y;
        r[10] += s[10] * di + b2.z; r[11] += s[11] * di + b2.w;
        r[12] += s[12] * di + b3.x; r[13] += s[13] * di + b3.y;
        r[14] += s[14] * di + b3.z; r[15] += s[15] * di + b3.w;
    }

    constexpr float inv3 = 1.0f / 3.0f;
    __half2 h[8];
#pragma unroll
    for (int k = 0; k < 8; ++k)
        h[k] = __floats2half2_rn(fmaxf(r[2 * k] * inv3, 0.f),
                                 fmaxf(r[2 * k + 1] * inv3, 0.f));
    i4v o0, o1;
    o0[0] = *reinterpret_cast<int*>(&h[0]);
    o0[1] = *reinterpret_cast<int*>(&h[1]);
    o0[2] = *reinterpret_cast<int*>(&h[2]);
    o0[3] = *reinterpret_cast<int*>(&h[3]);
    o1[0] = *reinterpret_cast<int*>(&h[4]);
    o1[1] = *reinterpret_cast<int*>(&h[5]);
    o1[2] = *reinterpret_cast<int*>(&h[6]);
    o1[3] = *reinterpret_cast<int*>(&h[7]);
    __half* op = h16 + (size_t)i * F + c;
    __builtin_nontemporal_store(o0, reinterpret_cast<i4v*>(op));
    __builtin_nontemporal_store(o1, reinterpret_cast<i4v*>(op + 8));
}

// ===========================================================================
// Layer-2 gather (pull, fp16 F=64 table): verbatim R9/R10.
// ===========================================================================
__global__ __launch_bounds__(256) void gather_l2_kernel(
    float* __restrict__ out, const __half* __restrict__ H,
    const float* __restrict__ dinv, const int* __restrict__ rp,
    const int* __restrict__ rpe, const int* __restrict__ srcs,
    const float* __restrict__ bias, int N, int EP)
{
    constexpr int F = 64, LPR = 8;

    int wave = threadIdx.x >> 6;
    int lane = threadIdx.x & 63;
    int sub  = lane >> 3;
    int lcol = lane & (LPR - 1);
    int i = (blockIdx.x * 4 + wave) * 8 + sub;
    if (i >= N) return;
    uint32_t c = (uint32_t)lcol * 8;         // half-index within row

    float r0 = 0.f, r1 = 0.f, r2 = 0.f, r3 = 0.f,
          r4 = 0.f, r5 = 0.f, r6 = 0.f, r7 = 0.f;

    for (int t = 0; t < T_REL; ++t) {
        const __half* Ht = H + (size_t)t * (N + 1) * F;
        const int*    st = srcs + (size_t)t * EP;
        float di = dinv[(size_t)t * N + i];

        float s0 = 0.f, s1 = 0.f, s2 = 0.f, s3 = 0.f,
              s4 = 0.f, s5 = 0.f, s6 = 0.f, s7 = 0.f;

        auto rowld = [&](int s) -> float4 {
            return *reinterpret_cast<const float4*>(Ht + ((uint32_t)s * (uint32_t)F + c));
        };
        auto acc8 = [&](float4 q) {
            const __half2* hp = reinterpret_cast<const __half2*>(&q);
            float2 f0 = __half22float2(hp[0]);
            float2 f1 = __half22float2(hp[1]);
            float2 f2 = __half22float2(hp[2]);
            float2 f3 = __half22float2(hp[3]);
            s0 += f0.x; s1 += f0.y; s2 += f1.x; s3 += f1.y;
            s4 += f2.x; s5 += f2.y; s6 += f3.x; s7 += f3.y;
        };

        int j   = rp [(size_t)t * N + i];
        int end = rpe[(size_t)t * N + i];

        for (; j + 8 <= end; j += 8) {
            i4v pa = __builtin_nontemporal_load(reinterpret_cast<const i4v*>(st + j));
            i4v pb = __builtin_nontemporal_load(reinterpret_cast<const i4v*>(st + j + 4));
            float4 q0 = rowld(pa[0]), q1 = rowld(pa[1]), q2 = rowld(pa[2]), q3 = rowld(pa[3]);
            float4 q4 = rowld(pb[0]), q5 = rowld(pb[1]), q6 = rowld(pb[2]), q7 = rowld(pb[3]);
            acc8(q0); acc8(q1); acc8(q2); acc8(q3);
            acc8(q4); acc8(q5); acc8(q6); acc8(q7);
        }
        if (j < end) {
            i4v pa = __builtin_nontemporal_load(reinterpret_cast<const i4v*>(st + j));
            float4 q0 = rowld(pa[0]), q1 = rowld(pa[1]), q2 = rowld(pa[2]), q3 = rowld(pa[3]);
            acc8(q0); acc8(q1); acc8(q2); acc8(q3);
        }

        const float4 b0 = *reinterpret_cast<const float4*>(bias + (size_t)t * F + c);
        const float4 b1 = *reinterpret_cast<const float4*>(bias + (size_t)t * F + c + 4);
        r0 += s0 * di + b0.x; r1 += s1 * di + b0.y;
        r2 += s2 * di + b0.z; r3 += s3 * di + b0.w;
        r4 += s4 * di + b1.x; r5 += s5 * di + b1.y;
        r6 += s6 * di + b1.z; r7 += s7 * di + b1.w;
    }

    constexpr float inv3 = 1.0f / 3.0f;
    f4v o0 = {r0 * inv3, r1 * inv3, r2 * inv3, r3 * inv3};
    f4v o1 = {r4 * inv3, r5 * inv3, r6 * inv3, r7 * inv3};
    float* op = out + (size_t)i * F + c;
    __builtin_nontemporal_store(o0, reinterpret_cast<f4v*>(op));
    __builtin_nontemporal_store(o1, reinterpret_cast<f4v*>(op + 4));
}

// ===========================================================================
extern "C" void kernel_launch(void* const* d_in, const int* in_sizes, int n_in,
                              void* d_out, int out_size, void* d_ws, size_t ws_size,
                              hipStream_t stream) {
    const float* x     = (const float*)d_in[0];
    const int*   edges = (const int*)  d_in[1];
    const float* W1    = (const float*)d_in[2];
    const float* b1    = (const float*)d_in[3];
    const float* W2    = (const float*)d_in[4];
    const float* b2    = (const float*)d_in[5];
    float* out = (float*)d_out;

    const int N  = in_sizes[0] / F_IN;
    const int E  = in_sizes[1] / (T_REL * 2);
    const int KB = (N + BRANGE - 1) >> BSHIFT;       // 782 buckets/relation
    const int NB = (E + CHUNK_E - 1) / CHUNK_E;      // 391 bin blocks/relation
    const int EP = E + (PADCAP + 4) * KB + 256;      // padded edges/relation

    auto align256 = [](size_t x_) { return (x_ + 255) & ~(size_t)255; };
    char* p = (char*)d_ws;
    float*   dinv   = (float*)p;   p += align256((size_t)T_REL * N * 4);
    int*     rp     = (int*)p;     p += align256((size_t)T_REL * N * 4);
    int*     rpe    = (int*)p;     p += align256((size_t)T_REL * N * 4);
    int*     bstart = (int*)p;     p += align256((size_t)T_REL * (KB + 1) * 4);
    int*     colSum = (int*)p;     p += align256((size_t)T_REL * KB * 4);
    int*     srcs   = (int*)p;     p += align256((size_t)T_REL * EP * 4);
    uint8_t* H8     = (uint8_t*)p; p += align256((size_t)T_REL * (N + 1) * F_HID);
    __half*  H2     = (__half*)p;  p += align256((size_t)T_REL * (N + 1) * F_OUT * 2);
    // Shared scratch region: h16 (25.6 MB, written by gather_l1) overlays the
    // CSR-build scratch (binned 19.2 + bHist/lStart 7.3 = 26.5 MB), which is
    // fully consumed by bucket_gather_sort before gather_l1 runs.
    char* share = p;
    __half*   h16    = (__half*)share;
    uint32_t* binned = (uint32_t*)share;
    char* q = share + align256((size_t)T_REL * E * 4);
    int*      bHist  = (int*)q;      q += align256((size_t)T_REL * NB * KB * 4);
    int*      lStart = (int*)q;      q += align256((size_t)T_REL * NB * KB * 4);
    size_t shareSz = (size_t)(q - share);
    size_t h16Sz   = (size_t)N * F_HID * 2;
    p = share + align256(shareSz > h16Sz ? shareSz : h16Sz);

    // ---- CSR build ----
    {
        dim3 g(NB, T_REL);
        bin_dense_kernel<<<g, 256, 0, stream>>>(bHist, lStart, binned,
                                                edges, E, KB, NB);
    }
    colsum_kernel<<<(T_REL * KB + 3) / 4, 256, 0, stream>>>(bHist, colSum, KB, NB);
    bucket_scan_kernel<<<T_REL, 1024, 0, stream>>>(colSum, bstart, KB);
    {
        dim3 g(KB, T_REL);
        bucket_gather_sort_kernel<<<g, 256, 0, stream>>>(
            bHist, lStart, bstart, binned, srcs, rp, rpe, dinv, KB, NB, N, E, EP);
    }

    // ---- layer 1: H8 = fp8((x@W1[t])*dinv*16), h16 = relu(mean+bias) ----
    mfma_gemm_fp8_kernel<<<N / 64 + 1, 256, 0, stream>>>(x, W1, H8, dinv, N);
    gather_l1_kernel<<<(N + 31) / 32, 256, 0, stream>>>(
        h16, H8, dinv, rp, rpe, srcs, b1, N, EP);

    // ---- layer 2: H2 = (h16@W2[t])*dinv fp16, out = mean+bias fp32 ----
    mfma_gemm_h16_kernel<<<N / 64 + 1, 256, 0, stream>>>(h16, W2, H2, dinv, N);
    gather_l2_kernel<<<(N + 31) / 32, 256, 0, stream>>>(
        out, H2, dinv, rp, rpe, srcs, b2, N, EP);
}